// Round 1
// 2700.378 us; speedup vs baseline: 1.1028x; 1.1028x over previous
//
#include <hip/hip_runtime.h>
#include <hip/hip_fp16.h>

#define DEVINL __device__ __forceinline__

constexpr int B = 256, S = 512;
constexpr int H0 = 64, H1 = 128, H2 = 256;

typedef _Float16 f16x8 __attribute__((ext_vector_type(8)));
typedef float f32x4 __attribute__((ext_vector_type(4)));
typedef _Float16 h2v __attribute__((ext_vector_type(2)));

DEVINL float fexp2(float x) { return __builtin_amdgcn_exp2f(x); }
DEVINL float frcp(float x) { return __builtin_amdgcn_rcpf(x); }
DEVINL float fsig(float x) { return frcp(1.f + fexp2(-1.44269504088896f * x)); }
DEVINL float ftanh_(float x) { return 1.f - 2.f * frcp(1.f + fexp2(2.88539008177793f * x)); }
DEVINL h2v as_h2(unsigned u) { union { unsigned u; h2v h; } x; x.u = u; return x.h; }
DEVINL float fdot2(unsigned a, unsigned b, float c) {
  return __builtin_amdgcn_fdot2(as_h2(a), as_h2(b), c, false);
}
union FU { uint4 u; f16x8 h; };
DEVINL f16x8 as_f16x8(uint4 u) { FU x; x.u = u; return x.h; }

// Row permutation: r' = mt*16 + quad*4 + reg  ->  channel = r'>>2, gate = r'&3.
// orig torch row = gate*Hch + channel. One lane of the C-frag then holds one
// channel's (i,f,g,o) quad (C: col=lane&15, row=(lane>>4)*4+reg).

// Pack W (fp32 [4*Hch][Kdim], torch gate rows) into fp16 A-frag order:
// wp[(mt*KT+kt)*64+lane] = 8 halves of W'[mt*16+(lane&15)][kt*32+(lane>>4)*8+j]
__global__ __launch_bounds__(256) void pack_frag(const float* __restrict__ w,
    uint4* __restrict__ wp, int Hch, int Kdim, int MT, int KT) {
  int o = blockIdx.x * 256 + threadIdx.x;
  if (o >= MT * KT * 64) return;
  int lane = o & 63, fk = o >> 6;
  int kt = fk % KT, mt = fk / KT;
  int rp = mt * 16 + (lane & 15);
  int orig = (rp & 3) * Hch + (rp >> 2);
  int k0 = kt * 32 + (lane >> 4) * 8;
  unsigned r[4];
#pragma unroll
  for (int p = 0; p < 4; ++p) {
    unsigned lo = __half_as_ushort(__float2half_rn(w[(size_t)orig * Kdim + k0 + 2 * p]));
    unsigned hi = __half_as_ushort(__float2half_rn(w[(size_t)orig * Kdim + k0 + 2 * p + 1]));
    r[p] = lo | (hi << 16);
  }
  uint4 v; v.x = r[0]; v.y = r[1]; v.z = r[2]; v.w = r[3];
  wp[o] = v;
}

__global__ __launch_bounds__(256) void pack_bias(const float* __restrict__ bih,
    const float* __restrict__ bhh, float* __restrict__ bs, int Hch) {
  int rp = blockIdx.x * 256 + threadIdx.x;
  if (rp >= 4 * Hch) return;
  int orig = (rp & 3) * Hch + (rp >> 2);
  bs[rp] = bih[orig] + bhh[orig];
}

__global__ void pack_wl(const float* __restrict__ wl, unsigned* __restrict__ wlp, int n) {
  int i = threadIdx.x;
  if (i < n) {
    unsigned lo = __half_as_ushort(__float2half_rn(wl[2 * i]));
    unsigned hi = __half_as_ushort(__float2half_rn(wl[2 * i + 1]));
    wlp[i] = lo | (hi << 16);
  }
}

__global__ __launch_bounds__(256) void f2h(const float* __restrict__ x,
                                           __half* __restrict__ y, int n8) {
  int i = blockIdx.x * 256 + threadIdx.x;
  if (i >= n8) return;
  float4 a = *(const float4*)(x + i * 8);
  float4 b = *(const float4*)(x + i * 8 + 4);
  __half h[8];
  h[0] = __float2half_rn(a.x); h[1] = __float2half_rn(a.y);
  h[2] = __float2half_rn(a.z); h[3] = __float2half_rn(a.w);
  h[4] = __float2half_rn(b.x); h[5] = __float2half_rn(b.y);
  h[6] = __float2half_rn(b.z); h[7] = __float2half_rn(b.w);
  *(uint4*)(y + i * 8) = *(const uint4*)h;
}

// MFMA input GEMM: preT[((bt*Sc+tl)*MT+mt)*64+lane] (C-frag f32x4) =
//   x[16 batch] @ WihP^T + bias.  Grid (bt, Sc/8, MT/16); 256 thr (4 waves).
template <int KT>
__global__ __launch_bounds__(256) void ingemm_mfma(const __half* __restrict__ x,
    const uint4* __restrict__ wp, const float* __restrict__ bs,
    f32x4* __restrict__ preT, int MT, int Sc, int t0) {
  constexpr int K = KT * 32;
  const int tid = threadIdx.x, w = tid >> 6, lane = tid & 63;
  const int n16 = lane & 15, quad = lane >> 4;
  const int bt = blockIdx.x, b0 = bt * 16;
  const int tlb = blockIdx.y * 8;
  const int mb = blockIdx.z * 16;

  uint4 areg[4][KT];
#pragma unroll
  for (int im = 0; im < 4; ++im)
#pragma unroll
    for (int kt = 0; kt < KT; ++kt)
      areg[im][kt] = wp[((size_t)(mb + w * 4 + im) * KT + kt) * 64 + lane];
  f32x4 bini[4];
#pragma unroll
  for (int im = 0; im < 4; ++im)
    bini[im] = *(const f32x4*)(bs + (mb + w * 4 + im) * 16 + quad * 4);

  for (int tt = 0; tt < 8; ++tt) {
    int t = t0 + tlb + tt;
    const __half* xr = x + ((size_t)(b0 + n16) * S + t) * K + quad * 8;
    uint4 bfr[KT];
#pragma unroll
    for (int kt = 0; kt < KT; ++kt) bfr[kt] = *(const uint4*)(xr + kt * 32);
    f32x4 acc[4];
#pragma unroll
    for (int im = 0; im < 4; ++im) acc[im] = bini[im];
#pragma unroll
    for (int kt = 0; kt < KT; ++kt)
#pragma unroll
      for (int im = 0; im < 4; ++im)
        acc[im] = __builtin_amdgcn_mfma_f32_16x16x32_f16(as_f16x8(areg[im][kt]),
                                                         as_f16x8(bfr[kt]), acc[im], 0, 0, 0);
#pragma unroll
    for (int im = 0; im < 4; ++im)
      preT[((size_t)(bt * Sc + tlb + tt) * MT + mb + w * 4 + im) * 64 + lane] = acc[im];
  }
}

// K-block over a compile-time k-tile range (keeps areg statically indexed).
#define KBLK(K0, K1)                                                              \
  _Pragma("unroll") for (int kt = (K0); kt < (K1); ++kt) {                        \
    f16x8 bfrag = as_f16x8(*(const uint4*)(hb + n16 * HP + kt * 32 + quad * 8));  \
    _Pragma("unroll") for (int im = 0; im < MTW; ++im)                            \
      acc[im] = __builtin_amdgcn_mfma_f32_16x16x32_f16(                           \
          as_f16x8(areg[im][kt]), bfrag, acc[im], 0, 0, 0);                       \
  }

// Weight-stationary recurrent scan, weights fully in registers.
// SPLIT=1: one WG per 16-batch group.
// SPLIT=2: two WGs split the m-dim. Exchange is latency-hidden:
//   - h exported straight from registers (lane-pair pack -> u32 relaxed agent
//     stores), flag = relaxed store after __syncthreads (vmcnt drain orders it);
//   - peer import DEFERRED one step, placed between own-half and peer-half
//     k-tiles of the next step so the mall round-trip hides under MFMAs;
//   - no threadfence (no per-step cache writeback/inv), no s_sleep(8) polling;
//   - 3 barriers/step (was 5).
template <int H, int SPLIT, bool FINAL>
__global__ __launch_bounds__(512) void scan_mfma(
    const uint4* __restrict__ wp, const f32x4* __restrict__ preT,
    __half* __restrict__ xout, float* __restrict__ out,
    const unsigned* __restrict__ wlp, const float* __restrict__ blp,
    float* __restrict__ sth, float* __restrict__ stc,
    unsigned* __restrict__ xh, int* __restrict__ flags,
    int Sc, int t0, int first) {
  constexpr int MT = H / 4;          // total m-tiles
  constexpr int MTO = MT / SPLIT;    // owned m-tiles
  constexpr int MTW = MTO / 8;       // per wave
  constexpr int KT = H / 32;
  constexpr int HP = H + 8;
  constexpr int CH_OWN = MTO * 4;    // owned channels

  __shared__ __half hb[16 * HP];
  __shared__ unsigned wls[FINAL ? H / 2 : 1];

  const int tid = threadIdx.x, w = tid >> 6, lane = tid & 63;
  const int n16 = lane & 15, quad = lane >> 4;
  int bt, half;
  if constexpr (SPLIT == 2) { bt = blockIdx.x & 15; half = blockIdx.x >> 4; }
  else { bt = blockIdx.x; half = 0; }
  const int b0 = bt * 16;
  const int mbase = half * MTO;

  uint4 areg[MTW][KT];
#pragma unroll
  for (int im = 0; im < MTW; ++im)
#pragma unroll
    for (int kt = 0; kt < KT; ++kt)
      areg[im][kt] = wp[((size_t)(mbase + w * MTW + im) * KT + kt) * 64 + lane];

  if constexpr (FINAL)
    for (int i = tid; i < H / 2; i += 512) wls[i] = wlp[i];

  float cst[MTW];
#pragma unroll
  for (int im = 0; im < MTW; ++im) {
    int ch = (mbase + w * MTW + im) * 4 + quad;
    cst[im] = first ? 0.f : stc[(size_t)(b0 + n16) * H + ch];
  }
  for (int i = tid; i < 16 * H; i += 512) {
    int n = i / H, ch = i % H;
    hb[n * HP + ch] = first ? __float2half_rn(0.f)
                            : __float2half_rn(sth[(size_t)(b0 + n) * H + ch]);
  }
  __syncthreads();

  const float bl0 = FINAL ? blp[0] : 0.f;

  auto emit_out = [&](int t_out) {
    if constexpr (FINAL) {
      if ((SPLIT == 1 || half == 0) && tid < 128) {
        int n = tid >> 3, seg = tid & 7;
        const unsigned* hrow = (const unsigned*)(hb + n * HP);
        float s = 0.f;
#pragma unroll
        for (int p = 0; p < 16; ++p) s = fdot2(hrow[seg * 16 + p], wls[seg * 16 + p], s);
        s += __shfl_xor(s, 1); s += __shfl_xor(s, 2); s += __shfl_xor(s, 4);
        if (seg == 0) out[(size_t)(b0 + n) * S + t_out] = ftanh_(s + bl0);
      }
    } else {
      if (tid < 16 * (H / 8)) {
        int n = tid / (H / 8), kq = tid % (H / 8);
        uint4 v = *(const uint4*)(hb + n * HP + kq * 8);
        *(uint4*)(xout + ((size_t)(b0 + n) * S + t_out) * H + kq * 8) = v;
      }
    }
  };

  auto import_peer = [&](int need) {  // peer h with flag value 'need' -> hb
    int fv = __hip_atomic_load(&flags[bt * 2 + (1 - half)], __ATOMIC_RELAXED,
                               __HIP_MEMORY_SCOPE_AGENT);
    while (fv < need) {
      __builtin_amdgcn_s_sleep(1);
      fv = __hip_atomic_load(&flags[bt * 2 + (1 - half)], __ATOMIC_RELAXED,
                             __HIP_MEMORY_SCOPE_AGENT);
    }
    const unsigned* src =
        xh + (((size_t)(need & 1) * 16 + bt) * 2 + (1 - half)) * (CH_OWN * 8);
#pragma unroll
    for (int jj = 0; jj < 2; ++jj) {
      int j = tid + jj * 512;
      unsigned v = __hip_atomic_load(src + j, __ATOMIC_RELAXED, __HIP_MEMORY_SCOPE_AGENT);
      int c = j >> 3, dn = j & 7;  // layout [c_local][n] halves, dword dn = batches 2dn,2dn+1
      hb[(2 * dn) * HP + (1 - half) * CH_OWN + c] =
          __ushort_as_half((unsigned short)(v & 0xffffu));
      hb[(2 * dn + 1) * HP + (1 - half) * CH_OWN + c] =
          __ushort_as_half((unsigned short)(v >> 16));
    }
  };

  f32x4 nxt[MTW];
#pragma unroll
  for (int im = 0; im < MTW; ++im)
    nxt[im] = preT[((size_t)(bt * Sc) * MT + mbase + w * MTW + im) * 64 + lane];

  for (int tl = 0; tl < Sc; ++tl) {
    f32x4 acc[MTW];
#pragma unroll
    for (int im = 0; im < MTW; ++im) acc[im] = nxt[im];
    if (tl + 1 < Sc) {  // prefetch next step's preT (consumed next iter)
#pragma unroll
      for (int im = 0; im < MTW; ++im)
        nxt[im] = preT[((size_t)(bt * Sc + tl + 1) * MT + mbase + w * MTW + im) * 64 + lane];
    }

    if constexpr (SPLIT == 2) {
      // own-half k-tiles first (own hb region was written locally last step);
      // the flag probe/import latency hides under these MFMAs.
      if (half == 0) { KBLK(0, KT / 2) } else { KBLK(KT / 2, KT) }
      if (tl > 0) {
        import_peer(t0 + tl);  // peer half of h(tl-1)
        __syncthreads();       // [#1] peer half visible to all waves
      }
      if (half == 0) { KBLK(KT / 2, KT) } else { KBLK(0, KT / 2) }
      if (tl > 0) emit_out(t0 + tl - 1);  // full h(tl-1) now in hb
    } else {
      if (tl > 0) emit_out(t0 + tl - 1);  // hb holds completed h(tl-1)
      KBLK(0, KT)
    }

    // gates (lane holds one channel's i,f,g,o per m-tile)
    __half hh[MTW];
#pragma unroll
    for (int im = 0; im < MTW; ++im) {
      float gi = fsig(acc[im][0]);
      float gf = fsig(acc[im][1]);
      float gg = ftanh_(acc[im][2]);
      float go = fsig(acc[im][3]);
      float cn = gf * cst[im] + gi * gg;
      cst[im] = cn;
      hh[im] = __float2half_rn(go * ftanh_(cn));
    }

    if constexpr (SPLIT == 2) {
      // export h(tl) straight from registers: lanes (2k,2k+1) share batches
      // (n16,n16+1) of the same channel -> pack to one dword via shfl_xor(1).
      const int s = t0 + tl + 1;
      unsigned* dst = xh + (((size_t)(s & 1) * 16 + bt) * 2 + half) * (CH_OWN * 8);
#pragma unroll
      for (int im = 0; im < MTW; ++im) {
        unsigned m = (unsigned)__half_as_ushort(hh[im]);
        unsigned o = (unsigned)__shfl_xor((int)m, 1);
        if (!(lane & 1)) {
          int cl = (w * MTW + im) * 4 + quad;  // channel local to this half
          __hip_atomic_store(dst + cl * 8 + (n16 >> 1), m | (o << 16),
                             __ATOMIC_RELAXED, __HIP_MEMORY_SCOPE_AGENT);
        }
      }
      __syncthreads();  // [#2] vmcnt drain: exports complete; hb(tl-1) reads done
      if (tid == 0)
        __hip_atomic_store(&flags[bt * 2 + half], s, __ATOMIC_RELAXED,
                           __HIP_MEMORY_SCOPE_AGENT);
#pragma unroll
      for (int im = 0; im < MTW; ++im)
        hb[n16 * HP + (mbase + w * MTW + im) * 4 + quad] = hh[im];
      __syncthreads();  // [#3] own half of h(tl) ready for next step's own-K
    } else {
      __syncthreads();  // A: hb(tl-1) reads done
#pragma unroll
      for (int im = 0; im < MTW; ++im)
        hb[n16 * HP + (mbase + w * MTW + im) * 4 + quad] = hh[im];
      __syncthreads();  // B: hb(tl) complete
    }
  }

  if constexpr (SPLIT == 2) {
    // tail: bring in peer half of h(Sc-1) for output + state carry
    import_peer(t0 + Sc);
    __syncthreads();
  }

  emit_out(t0 + Sc - 1);

  // carry state (sth full range — duplicate identical writes for SPLIT=2 are benign)
  for (int i = tid; i < 16 * H; i += 512) {
    int n = i / H, ch = i % H;
    sth[(size_t)(b0 + n) * H + ch] = __half2float(hb[n * HP + ch]);
  }
#pragma unroll
  for (int im = 0; im < MTW; ++im) {
    int ch = (mbase + w * MTW + im) * 4 + quad;
    stc[(size_t)(b0 + n16) * H + ch] = cst[im];
  }
}
#undef KBLK

extern "C" void kernel_launch(void* const* d_in, const int* in_sizes, int n_in,
                              void* d_out, int out_size, void* d_ws, size_t ws_size,
                              hipStream_t stream) {
  (void)in_sizes; (void)n_in; (void)out_size;
  const float* noise = (const float*)d_in[0];
  const float* Wih0 = (const float*)d_in[1];
  const float* Whh0 = (const float*)d_in[2];
  const float* bih0 = (const float*)d_in[3];
  const float* bhh0 = (const float*)d_in[4];
  const float* Wih1 = (const float*)d_in[5];
  const float* Whh1 = (const float*)d_in[6];
  const float* bih1 = (const float*)d_in[7];
  const float* bhh1 = (const float*)d_in[8];
  const float* Wih2 = (const float*)d_in[9];
  const float* Whh2 = (const float*)d_in[10];
  const float* bih2 = (const float*)d_in[11];
  const float* bhh2 = (const float*)d_in[12];
  const float* Wl = (const float*)d_in[13];
  const float* bl = (const float*)d_in[14];
  float* out = (float*)d_out;

  char* p = (char*)d_ws;
  auto alloc = [&](size_t bytes) {
    char* r = p;
    p += (bytes + 255) & ~(size_t)255;
    return r;
  };
  // A-frag packed weights (fp16): recurrent + input
  uint4* wpH0 = (uint4*)alloc((size_t)16 * 2 * 1024);
  uint4* wpH1 = (uint4*)alloc((size_t)32 * 4 * 1024);
  uint4* wpH2 = (uint4*)alloc((size_t)64 * 8 * 1024);
  uint4* wpI0 = (uint4*)alloc((size_t)16 * 1 * 1024);
  uint4* wpI1 = (uint4*)alloc((size_t)32 * 2 * 1024);
  uint4* wpI2 = (uint4*)alloc((size_t)64 * 4 * 1024);
  float* bs0 = (float*)alloc(256 * 4);
  float* bs1 = (float*)alloc(512 * 4);
  float* bs2 = (float*)alloc(1024 * 4);
  unsigned* wlp = (unsigned*)alloc(128 * 4);
  // state carry
  float* sh0 = (float*)alloc((size_t)B * H0 * 4);
  float* sc0 = (float*)alloc((size_t)B * H0 * 4);
  float* sh1 = (float*)alloc((size_t)B * H1 * 4);
  float* sc1 = (float*)alloc((size_t)B * H1 * 4);
  float* sh2 = (float*)alloc((size_t)B * H2 * 4);
  float* sc2 = (float*)alloc((size_t)B * H2 * 4);
  // activations (fp16)
  __half* x0 = (__half*)alloc((size_t)B * S * 32 * 2);
  __half* x1 = (__half*)alloc((size_t)B * S * H0 * 2);
  __half* x2 = (__half*)alloc((size_t)B * S * H1 * 2);
  // cross-WG exchange buffers + flags (layer 2)
  unsigned* xh = (unsigned*)alloc((size_t)2 * 16 * 2 * 1024 * 4);
  int* flags = (int*)alloc(64 * 4);
  size_t fixed = (size_t)(p - (char*)d_ws);
  int Sc = 128;  // time-chunk keeps preT bounded / L3-resident
  while (Sc > 16 && fixed + (size_t)B * Sc * 1024 * 4 > ws_size) Sc >>= 1;
  float* preT = (float*)alloc((size_t)B * Sc * 1024 * 4);

  // flags must start < t0+1 each launch (graph replay leaves them at S)
  hipMemsetAsync(flags, 0, 64 * sizeof(int), stream);

  // ---- packing (every call; deterministic) ----
  pack_frag<<<(16 * 2 * 64 + 255) / 256, 256, 0, stream>>>(Whh0, wpH0, 64, 64, 16, 2);
  pack_frag<<<(32 * 4 * 64 + 255) / 256, 256, 0, stream>>>(Whh1, wpH1, 128, 128, 32, 4);
  pack_frag<<<(64 * 8 * 64 + 255) / 256, 256, 0, stream>>>(Whh2, wpH2, 256, 256, 64, 8);
  pack_frag<<<(16 * 1 * 64 + 255) / 256, 256, 0, stream>>>(Wih0, wpI0, 64, 32, 16, 1);
  pack_frag<<<(32 * 2 * 64 + 255) / 256, 256, 0, stream>>>(Wih1, wpI1, 128, 64, 32, 2);
  pack_frag<<<(64 * 4 * 64 + 255) / 256, 256, 0, stream>>>(Wih2, wpI2, 256, 128, 64, 4);
  pack_bias<<<1, 256, 0, stream>>>(bih0, bhh0, bs0, 64);
  pack_bias<<<2, 256, 0, stream>>>(bih1, bhh1, bs1, 128);
  pack_bias<<<4, 256, 0, stream>>>(bih2, bhh2, bs2, 256);
  pack_wl<<<1, 128, 0, stream>>>(Wl, wlp, 128);
  f2h<<<(B * S * 32 / 8 + 255) / 256, 256, 0, stream>>>(noise, x0, B * S * 32 / 8);

  for (int c = 0; c < S / Sc; ++c) {
    int t0 = c * Sc;
    ingemm_mfma<1><<<dim3(16, Sc / 8, 1), 256, 0, stream>>>(x0, wpI0, bs0,
                                                            (f32x4*)preT, 16, Sc, t0);
    scan_mfma<64, 1, false><<<16, 512, 0, stream>>>(
        wpH0, (const f32x4*)preT, x1, nullptr, nullptr, nullptr, sh0, sc0,
        nullptr, nullptr, Sc, t0, c == 0);
    ingemm_mfma<2><<<dim3(16, Sc / 8, 2), 256, 0, stream>>>(x1, wpI1, bs1,
                                                            (f32x4*)preT, 32, Sc, t0);
    scan_mfma<128, 1, false><<<16, 512, 0, stream>>>(
        wpH1, (const f32x4*)preT, x2, nullptr, nullptr, nullptr, sh1, sc1,
        nullptr, nullptr, Sc, t0, c == 0);
    ingemm_mfma<4><<<dim3(16, Sc / 8, 4), 256, 0, stream>>>(x2, wpI2, bs2,
                                                            (f32x4*)preT, 64, Sc, t0);
    scan_mfma<256, 2, true><<<32, 512, 0, stream>>>(
        wpH2, (const f32x4*)preT, nullptr, out, wlp, bl, sh2, sc2,
        xh, flags, Sc, t0, c == 0);
  }
}

// Round 4
// 2228.605 us; speedup vs baseline: 1.3362x; 1.2117x over previous
//
#include <hip/hip_runtime.h>
#include <hip/hip_fp16.h>

#define DEVINL __device__ __forceinline__

constexpr int B = 256, S = 512;
constexpr int H0 = 64, H1 = 128, H2 = 256;

typedef _Float16 f16x8 __attribute__((ext_vector_type(8)));
typedef float f32x4 __attribute__((ext_vector_type(4)));
typedef _Float16 h2v __attribute__((ext_vector_type(2)));

DEVINL float fexp2(float x) { return __builtin_amdgcn_exp2f(x); }
DEVINL float frcp(float x) { return __builtin_amdgcn_rcpf(x); }
DEVINL float fsig(float x) { return frcp(1.f + fexp2(-1.44269504088896f * x)); }
DEVINL float ftanh_(float x) { return 1.f - 2.f * frcp(1.f + fexp2(2.88539008177793f * x)); }
DEVINL h2v as_h2(unsigned u) { union { unsigned u; h2v h; } x; x.u = u; return x.h; }
DEVINL float fdot2(unsigned a, unsigned b, float c) {
  return __builtin_amdgcn_fdot2(as_h2(a), as_h2(b), c, false);
}
union FU { uint4 u; f16x8 h; };
DEVINL f16x8 as_f16x8(uint4 u) { FU x; x.u = u; return x.h; }

// Agent-scope (mall-coherent) 8-byte atomic load/store. A single aligned
// dwordx2 transaction cannot tear, so {seq,data} travel together: the
// consumer validates seq in-band instead of a separate flag+drain protocol.
DEVINL unsigned long long agldull(unsigned long long* p) {
  return __hip_atomic_load(p, __ATOMIC_RELAXED, __HIP_MEMORY_SCOPE_AGENT);
}
DEVINL void agstull(unsigned long long* p, unsigned long long v) {
  __hip_atomic_store(p, v, __ATOMIC_RELAXED, __HIP_MEMORY_SCOPE_AGENT);
}

// Row permutation: r' = mt*16 + quad*4 + reg  ->  channel = r'>>2, gate = r'&3.
// orig torch row = gate*Hch + channel. One lane of the C-frag then holds one
// channel's (i,f,g,o) quad (C: col=lane&15, row=(lane>>4)*4+reg).

// Pack W (fp32 [4*Hch][Kdim], torch gate rows) into fp16 A-frag order:
// wp[(mt*KT+kt)*64+lane] = 8 halves of W'[mt*16+(lane&15)][kt*32+(lane>>4)*8+j]
__global__ __launch_bounds__(256) void pack_frag(const float* __restrict__ w,
    uint4* __restrict__ wp, int Hch, int Kdim, int MT, int KT) {
  int o = blockIdx.x * 256 + threadIdx.x;
  if (o >= MT * KT * 64) return;
  int lane = o & 63, fk = o >> 6;
  int kt = fk % KT, mt = fk / KT;
  int rp = mt * 16 + (lane & 15);
  int orig = (rp & 3) * Hch + (rp >> 2);
  int k0 = kt * 32 + (lane >> 4) * 8;
  unsigned r[4];
#pragma unroll
  for (int p = 0; p < 4; ++p) {
    unsigned lo = __half_as_ushort(__float2half_rn(w[(size_t)orig * Kdim + k0 + 2 * p]));
    unsigned hi = __half_as_ushort(__float2half_rn(w[(size_t)orig * Kdim + k0 + 2 * p + 1]));
    r[p] = lo | (hi << 16);
  }
  uint4 v; v.x = r[0]; v.y = r[1]; v.z = r[2]; v.w = r[3];
  wp[o] = v;
}

__global__ __launch_bounds__(256) void pack_bias(const float* __restrict__ bih,
    const float* __restrict__ bhh, float* __restrict__ bs, int Hch) {
  int rp = blockIdx.x * 256 + threadIdx.x;
  if (rp >= 4 * Hch) return;
  int orig = (rp & 3) * Hch + (rp >> 2);
  bs[rp] = bih[orig] + bhh[orig];
}

__global__ void pack_wl(const float* __restrict__ wl, unsigned* __restrict__ wlp, int n) {
  int i = threadIdx.x;
  if (i < n) {
    unsigned lo = __half_as_ushort(__float2half_rn(wl[2 * i]));
    unsigned hi = __half_as_ushort(__float2half_rn(wl[2 * i + 1]));
    wlp[i] = lo | (hi << 16);
  }
}

__global__ __launch_bounds__(256) void f2h(const float* __restrict__ x,
                                           __half* __restrict__ y, int n8) {
  int i = blockIdx.x * 256 + threadIdx.x;
  if (i >= n8) return;
  float4 a = *(const float4*)(x + i * 8);
  float4 b = *(const float4*)(x + i * 8 + 4);
  __half h[8];
  h[0] = __float2half_rn(a.x); h[1] = __float2half_rn(a.y);
  h[2] = __float2half_rn(a.z); h[3] = __float2half_rn(a.w);
  h[4] = __float2half_rn(b.x); h[5] = __float2half_rn(b.y);
  h[6] = __float2half_rn(b.z); h[7] = __float2half_rn(b.w);
  *(uint4*)(y + i * 8) = *(const uint4*)h;
}

// MFMA input GEMM: preT[((bt*Sc+tl)*MT+mt)*64+lane] (C-frag f32x4) =
//   x[16 batch] @ WihP^T + bias.  Grid (bt, Sc/8, MT/16); 256 thr (4 waves).
template <int KT>
__global__ __launch_bounds__(256) void ingemm_mfma(const __half* __restrict__ x,
    const uint4* __restrict__ wp, const float* __restrict__ bs,
    f32x4* __restrict__ preT, int MT, int Sc, int t0) {
  constexpr int K = KT * 32;
  const int tid = threadIdx.x, w = tid >> 6, lane = tid & 63;
  const int n16 = lane & 15, quad = lane >> 4;
  const int bt = blockIdx.x, b0 = bt * 16;
  const int tlb = blockIdx.y * 8;
  const int mb = blockIdx.z * 16;

  uint4 areg[4][KT];
#pragma unroll
  for (int im = 0; im < 4; ++im)
#pragma unroll
    for (int kt = 0; kt < KT; ++kt)
      areg[im][kt] = wp[((size_t)(mb + w * 4 + im) * KT + kt) * 64 + lane];
  f32x4 bini[4];
#pragma unroll
  for (int im = 0; im < 4; ++im)
    bini[im] = *(const f32x4*)(bs + (mb + w * 4 + im) * 16 + quad * 4);

  for (int tt = 0; tt < 8; ++tt) {
    int t = t0 + tlb + tt;
    const __half* xr = x + ((size_t)(b0 + n16) * S + t) * K + quad * 8;
    uint4 bfr[KT];
#pragma unroll
    for (int kt = 0; kt < KT; ++kt) bfr[kt] = *(const uint4*)(xr + kt * 32);
    f32x4 acc[4];
#pragma unroll
    for (int im = 0; im < 4; ++im) acc[im] = bini[im];
#pragma unroll
    for (int kt = 0; kt < KT; ++kt)
#pragma unroll
      for (int im = 0; im < 4; ++im)
        acc[im] = __builtin_amdgcn_mfma_f32_16x16x32_f16(as_f16x8(areg[im][kt]),
                                                         as_f16x8(bfr[kt]), acc[im], 0, 0, 0);
#pragma unroll
    for (int im = 0; im < 4; ++im)
      preT[((size_t)(bt * Sc + tlb + tt) * MT + mb + w * 4 + im) * 64 + lane] = acc[im];
  }
}

// K-block over a compile-time k-tile range (keeps areg statically indexed).
#define KBLK(K0, K1)                                                              \
  _Pragma("unroll") for (int kt = (K0); kt < (K1); ++kt) {                        \
    f16x8 bfrag = as_f16x8(*(const uint4*)(hb + n16 * HP + kt * 32 + quad * 8));  \
    _Pragma("unroll") for (int im = 0; im < MTW; ++im)                            \
      acc[im] = __builtin_amdgcn_mfma_f32_16x16x32_f16(                           \
          as_f16x8(areg[im][kt]), bfrag, acc[im], 0, 0, 0);                       \
  }

// Weight-stationary recurrent scan, weights fully in registers.
// SPLIT=1: one WG per 16-batch group (R1-proven skeleton, unchanged).
// SPLIT=2: two WGs split the m-dim. h exchange is FLAGLESS seq-tagged:
//   export: one 8B agent-atomic store per dword = {seq=hid+1 | data}, fire
//     and forget (no vmcnt drain, no flag store);
//   import: 8B agent-atomic loads + in-band seq validation, per-wave retry.
//   Steady state = ONE mall round trip (data usually already posted).
//   Deadlock-free: producer never blocks before exporting; exact-match seq
//   makes stale/partial data just "not ready"; slot overwrite (parity ping-
//   pong) is ordered by the recurrence's own data dependency.
template <int H, int SPLIT, bool FINAL>
__global__ __launch_bounds__(512) void scan_mfma(
    const uint4* __restrict__ wp, const f32x4* __restrict__ preT,
    __half* __restrict__ xout, float* __restrict__ out,
    const unsigned* __restrict__ wlp, const float* __restrict__ blp,
    float* __restrict__ sth, float* __restrict__ stc,
    unsigned long long* __restrict__ xh,
    int Sc, int t0, int first) {
  constexpr int MT = H / 4;          // total m-tiles
  constexpr int MTO = MT / SPLIT;    // owned m-tiles
  constexpr int MTW = MTO / 8;       // per wave
  constexpr int KT = H / 32;
  constexpr int HP = H + 8;
  constexpr int CH_OWN = MTO * 4;    // owned channels

  __shared__ __half hb[16 * HP];
  __shared__ unsigned wls[FINAL ? H / 2 : 1];

  const int tid = threadIdx.x, w = tid >> 6, lane = tid & 63;
  const int n16 = lane & 15, quad = lane >> 4;
  int bt, half;
  if constexpr (SPLIT == 2) { bt = blockIdx.x & 15; half = blockIdx.x >> 4; }
  else { bt = blockIdx.x; half = 0; }
  const int b0 = bt * 16;
  const int mbase = half * MTO;

  uint4 areg[MTW][KT];
#pragma unroll
  for (int im = 0; im < MTW; ++im)
#pragma unroll
    for (int kt = 0; kt < KT; ++kt)
      areg[im][kt] = wp[((size_t)(mbase + w * MTW + im) * KT + kt) * 64 + lane];

  if constexpr (FINAL)
    for (int i = tid; i < H / 2; i += 512) wls[i] = wlp[i];

  float cst[MTW];
#pragma unroll
  for (int im = 0; im < MTW; ++im) {
    int ch = (mbase + w * MTW + im) * 4 + quad;
    cst[im] = first ? 0.f : stc[(size_t)(b0 + n16) * H + ch];
  }
  for (int i = tid; i < 16 * H; i += 512) {
    int n = i / H, ch = i % H;
    hb[n * HP + ch] = first ? __float2half_rn(0.f)
                            : __float2half_rn(sth[(size_t)(b0 + n) * H + ch]);
  }
  __syncthreads();

  const float bl0 = FINAL ? blp[0] : 0.f;

  auto emit_out = [&](int t_out) {
    if constexpr (FINAL) {
      if ((SPLIT == 1 || half == 0) && tid < 128) {
        int n = tid >> 3, seg = tid & 7;
        const unsigned* hrow = (const unsigned*)(hb + n * HP);
        float s = 0.f;
#pragma unroll
        for (int p = 0; p < 16; ++p) s = fdot2(hrow[seg * 16 + p], wls[seg * 16 + p], s);
        s += __shfl_xor(s, 1); s += __shfl_xor(s, 2); s += __shfl_xor(s, 4);
        if (seg == 0) out[(size_t)(b0 + n) * S + t_out] = ftanh_(s + bl0);
      }
    } else {
      if (tid < 16 * (H / 8)) {
        int n = tid / (H / 8), kq = tid % (H / 8);
        uint4 v = *(const uint4*)(hb + n * HP + kq * 8);
        *(uint4*)(xout + ((size_t)(b0 + n) * S + t_out) * H + kq * 8) = v;
      }
    }
  };

  // import peer half of h(hid) -> hb; validates in-band seq, per-wave retry.
  auto import_peer = [&](int hid) {
    const unsigned seq = (unsigned)(hid + 1);
    unsigned long long* src =
        xh + (((size_t)(hid & 1) * 16 + bt) * 2 + (1 - half)) * 1024;
    int j0 = w * 128 + lane;  // this wave's share: j0 and j0+64
    unsigned long long v0, v1;
    for (;;) {
      v0 = agldull(src + j0);
      v1 = agldull(src + j0 + 64);
      bool ok = ((unsigned)(v0 >> 32) == seq) && ((unsigned)(v1 >> 32) == seq);
      if (__all(ok)) break;
      __builtin_amdgcn_s_sleep(1);
    }
    int c0 = j0 >> 3, dn0 = j0 & 7;  // dword j = c*8 + dn; batches 2dn,2dn+1
    hb[(2 * dn0) * HP + (1 - half) * CH_OWN + c0] =
        __ushort_as_half((unsigned short)(v0 & 0xffffu));
    hb[(2 * dn0 + 1) * HP + (1 - half) * CH_OWN + c0] =
        __ushort_as_half((unsigned short)((v0 >> 16) & 0xffffu));
    int j1 = j0 + 64, c1 = j1 >> 3, dn1 = j1 & 7;
    hb[(2 * dn1) * HP + (1 - half) * CH_OWN + c1] =
        __ushort_as_half((unsigned short)(v1 & 0xffffu));
    hb[(2 * dn1 + 1) * HP + (1 - half) * CH_OWN + c1] =
        __ushort_as_half((unsigned short)((v1 >> 16) & 0xffffu));
  };

  f32x4 nxt[MTW];
#pragma unroll
  for (int im = 0; im < MTW; ++im)
    nxt[im] = preT[((size_t)(bt * Sc) * MT + mbase + w * MTW + im) * 64 + lane];

  for (int tl = 0; tl < Sc; ++tl) {
    f32x4 acc[MTW];
#pragma unroll
    for (int im = 0; im < MTW; ++im) acc[im] = nxt[im];
    if (tl + 1 < Sc) {  // prefetch next step's preT (consumed next iter)
#pragma unroll
      for (int im = 0; im < MTW; ++im)
        nxt[im] = preT[((size_t)(bt * Sc + tl + 1) * MT + mbase + w * MTW + im) * 64 + lane];
    }

    if constexpr (SPLIT == 2) {
      // own-half k-tiles first; import latency hides under them.
      if (half == 0) { KBLK(0, KT / 2) } else { KBLK(KT / 2, KT) }
      if (tl > 0) {
        import_peer(t0 + tl - 1);  // peer half of h(tl-1), seq-validated
        __syncthreads();           // [#1] peer half visible to all waves
      }
      if (half == 0) { KBLK(KT / 2, KT) } else { KBLK(0, KT / 2) }
      if (tl > 0) emit_out(t0 + tl - 1);  // full h(tl-1) now in hb
    } else {
      if (tl > 0) emit_out(t0 + tl - 1);  // hb holds completed h(tl-1)
      KBLK(0, KT)
    }

    // gates (lane holds one channel's i,f,g,o per m-tile)
    __half hh[MTW];
#pragma unroll
    for (int im = 0; im < MTW; ++im) {
      float gi = fsig(acc[im][0]);
      float gf = fsig(acc[im][1]);
      float gg = ftanh_(acc[im][2]);
      float go = fsig(acc[im][3]);
      float cn = gf * cst[im] + gi * gg;
      cst[im] = cn;
      hh[im] = __float2half_rn(go * ftanh_(cn));
    }

    if constexpr (SPLIT == 2) {
      // export h(tl) straight from registers: lanes (2k,2k+1) share batches
      // (n16,n16+1) of the same channel -> one {seq|data} 8B atomic store.
      const int hid = t0 + tl;
      const unsigned seq = (unsigned)(hid + 1);
      unsigned long long* dst =
          xh + (((size_t)(hid & 1) * 16 + bt) * 2 + half) * 1024;
#pragma unroll
      for (int im = 0; im < MTW; ++im) {
        unsigned m = (unsigned)__half_as_ushort(hh[im]);
        unsigned o = (unsigned)__shfl_xor((int)m, 1);
        if (!(lane & 1)) {
          int cl = (w * MTW + im) * 4 + quad;  // channel local to this half
          agstull(dst + cl * 8 + (n16 >> 1),
                  ((unsigned long long)seq << 32) | (unsigned long long)(m | (o << 16)));
        }
      }
      __syncthreads();  // [#2] hb(tl-1) reads (KBLK + emit) done
#pragma unroll
      for (int im = 0; im < MTW; ++im)
        hb[n16 * HP + (mbase + w * MTW + im) * 4 + quad] = hh[im];
      __syncthreads();  // [#3] own half of h(tl) ready for next step
    } else {
      __syncthreads();  // A: hb(tl-1) reads done
#pragma unroll
      for (int im = 0; im < MTW; ++im)
        hb[n16 * HP + (mbase + w * MTW + im) * 4 + quad] = hh[im];
      __syncthreads();  // B: hb(tl) complete
    }
  }

  if constexpr (SPLIT == 2) {
    // tail: bring in peer half of h(Sc-1) for output + state carry
    import_peer(t0 + Sc - 1);
    __syncthreads();
  }

  emit_out(t0 + Sc - 1);

  // carry state (sth full range — duplicate identical writes for SPLIT=2 are benign)
  for (int i = tid; i < 16 * H; i += 512) {
    int n = i / H, ch = i % H;
    sth[(size_t)(b0 + n) * H + ch] = __half2float(hb[n * HP + ch]);
  }
#pragma unroll
  for (int im = 0; im < MTW; ++im) {
    int ch = (mbase + w * MTW + im) * 4 + quad;
    stc[(size_t)(b0 + n16) * H + ch] = cst[im];
  }
}
#undef KBLK

extern "C" void kernel_launch(void* const* d_in, const int* in_sizes, int n_in,
                              void* d_out, int out_size, void* d_ws, size_t ws_size,
                              hipStream_t stream) {
  (void)in_sizes; (void)n_in; (void)out_size;
  const float* noise = (const float*)d_in[0];
  const float* Wih0 = (const float*)d_in[1];
  const float* Whh0 = (const float*)d_in[2];
  const float* bih0 = (const float*)d_in[3];
  const float* bhh0 = (const float*)d_in[4];
  const float* Wih1 = (const float*)d_in[5];
  const float* Whh1 = (const float*)d_in[6];
  const float* bih1 = (const float*)d_in[7];
  const float* bhh1 = (const float*)d_in[8];
  const float* Wih2 = (const float*)d_in[9];
  const float* Whh2 = (const float*)d_in[10];
  const float* bih2 = (const float*)d_in[11];
  const float* bhh2 = (const float*)d_in[12];
  const float* Wl = (const float*)d_in[13];
  const float* bl = (const float*)d_in[14];
  float* out = (float*)d_out;

  char* p = (char*)d_ws;
  auto alloc = [&](size_t bytes) {
    char* r = p;
    p += (bytes + 255) & ~(size_t)255;
    return r;
  };
  // A-frag packed weights (fp16): recurrent + input
  uint4* wpH0 = (uint4*)alloc((size_t)16 * 2 * 1024);
  uint4* wpH1 = (uint4*)alloc((size_t)32 * 4 * 1024);
  uint4* wpH2 = (uint4*)alloc((size_t)64 * 8 * 1024);
  uint4* wpI0 = (uint4*)alloc((size_t)16 * 1 * 1024);
  uint4* wpI1 = (uint4*)alloc((size_t)32 * 2 * 1024);
  uint4* wpI2 = (uint4*)alloc((size_t)64 * 4 * 1024);
  float* bs0 = (float*)alloc(256 * 4);
  float* bs1 = (float*)alloc(512 * 4);
  float* bs2 = (float*)alloc(1024 * 4);
  unsigned* wlp = (unsigned*)alloc(128 * 4);
  // state carry
  float* sh0 = (float*)alloc((size_t)B * H0 * 4);
  float* sc0 = (float*)alloc((size_t)B * H0 * 4);
  float* sh1 = (float*)alloc((size_t)B * H1 * 4);
  float* sc1 = (float*)alloc((size_t)B * H1 * 4);
  float* sh2 = (float*)alloc((size_t)B * H2 * 4);
  float* sc2 = (float*)alloc((size_t)B * H2 * 4);
  // activations (fp16)
  __half* x0 = (__half*)alloc((size_t)B * S * 32 * 2);
  __half* x1 = (__half*)alloc((size_t)B * S * H0 * 2);
  __half* x2 = (__half*)alloc((size_t)B * S * H1 * 2);
  // cross-WG exchange: {seq|data} ull per dword-pair, 2 parity x 16 bt x 2 half
  unsigned long long* xh = (unsigned long long*)alloc((size_t)2 * 16 * 2 * 1024 * 8);
  size_t fixed = (size_t)(p - (char*)d_ws);
  int Sc = 128;  // time-chunk keeps preT bounded / L3-resident
  while (Sc > 16 && fixed + (size_t)B * Sc * 1024 * 4 > ws_size) Sc >>= 1;
  float* preT = (float*)alloc((size_t)B * Sc * 1024 * 4);

  // xh must be zeroed each launch: seq values repeat across graph replays and
  // inputs may be re-poisoned, so stale {seq|data} would validate wrongly.
  hipMemsetAsync(xh, 0, (size_t)2 * 16 * 2 * 1024 * 8, stream);

  // ---- packing (every call; deterministic) ----
  pack_frag<<<(16 * 2 * 64 + 255) / 256, 256, 0, stream>>>(Whh0, wpH0, 64, 64, 16, 2);
  pack_frag<<<(32 * 4 * 64 + 255) / 256, 256, 0, stream>>>(Whh1, wpH1, 128, 128, 32, 4);
  pack_frag<<<(64 * 8 * 64 + 255) / 256, 256, 0, stream>>>(Whh2, wpH2, 256, 256, 64, 8);
  pack_frag<<<(16 * 1 * 64 + 255) / 256, 256, 0, stream>>>(Wih0, wpI0, 64, 32, 16, 1);
  pack_frag<<<(32 * 2 * 64 + 255) / 256, 256, 0, stream>>>(Wih1, wpI1, 128, 64, 32, 2);
  pack_frag<<<(64 * 4 * 64 + 255) / 256, 256, 0, stream>>>(Wih2, wpI2, 256, 128, 64, 4);
  pack_bias<<<1, 256, 0, stream>>>(bih0, bhh0, bs0, 64);
  pack_bias<<<2, 256, 0, stream>>>(bih1, bhh1, bs1, 128);
  pack_bias<<<4, 256, 0, stream>>>(bih2, bhh2, bs2, 256);
  pack_wl<<<1, 128, 0, stream>>>(Wl, wlp, 128);
  f2h<<<(B * S * 32 / 8 + 255) / 256, 256, 0, stream>>>(noise, x0, B * S * 32 / 8);

  for (int c = 0; c < S / Sc; ++c) {
    int t0 = c * Sc;
    ingemm_mfma<1><<<dim3(16, Sc / 8, 1), 256, 0, stream>>>(x0, wpI0, bs0,
                                                            (f32x4*)preT, 16, Sc, t0);
    scan_mfma<64, 1, false><<<16, 512, 0, stream>>>(
        wpH0, (const f32x4*)preT, x1, nullptr, nullptr, nullptr, sh0, sc0,
        nullptr, Sc, t0, c == 0);
    ingemm_mfma<2><<<dim3(16, Sc / 8, 2), 256, 0, stream>>>(x1, wpI1, bs1,
                                                            (f32x4*)preT, 32, Sc, t0);
    scan_mfma<128, 1, false><<<16, 512, 0, stream>>>(
        wpH1, (const f32x4*)preT, x2, nullptr, nullptr, nullptr, sh1, sc1,
        nullptr, Sc, t0, c == 0);
    ingemm_mfma<4><<<dim3(16, Sc / 8, 4), 256, 0, stream>>>(x2, wpI2, bs2,
                                                            (f32x4*)preT, 64, Sc, t0);
    scan_mfma<256, 2, true><<<32, 512, 0, stream>>>(
        wpH2, (const f32x4*)preT, nullptr, out, wlp, bl, sh2, sc2,
        xh, Sc, t0, c == 0);
  }
}

// Round 5
// 1906.674 us; speedup vs baseline: 1.5618x; 1.1688x over previous
//
#include <hip/hip_runtime.h>
#include <hip/hip_fp16.h>

#define DEVINL __device__ __forceinline__

constexpr int B = 256, S = 512;
constexpr int H0 = 64, H1 = 128, H2 = 256;

typedef _Float16 f16x8 __attribute__((ext_vector_type(8)));
typedef float f32x4 __attribute__((ext_vector_type(4)));
typedef _Float16 h2v __attribute__((ext_vector_type(2)));

DEVINL float fexp2(float x) { return __builtin_amdgcn_exp2f(x); }
DEVINL float frcp(float x) { return __builtin_amdgcn_rcpf(x); }
DEVINL float fsig(float x) { return frcp(1.f + fexp2(-1.44269504088896f * x)); }
DEVINL float ftanh_(float x) { return 1.f - 2.f * frcp(1.f + fexp2(2.88539008177793f * x)); }
DEVINL h2v as_h2(unsigned u) { union { unsigned u; h2v h; } x; x.u = u; return x.h; }
DEVINL float fdot2(unsigned a, unsigned b, float c) {
  return __builtin_amdgcn_fdot2(as_h2(a), as_h2(b), c, false);
}
union FU { uint4 u; f16x8 h; };
DEVINL f16x8 as_f16x8(uint4 u) { FU x; x.u = u; return x.h; }

// Agent-scope (mall-coherent) 8-byte atomic load/store. A single aligned
// dwordx2 transaction cannot tear, so {seq,data} travel together and the
// consumer validates seq in-band (R4-proven protocol).
DEVINL unsigned long long agldull(unsigned long long* p) {
  return __hip_atomic_load(p, __ATOMIC_RELAXED, __HIP_MEMORY_SCOPE_AGENT);
}
DEVINL void agstull(unsigned long long* p, unsigned long long v) {
  __hip_atomic_store(p, v, __ATOMIC_RELAXED, __HIP_MEMORY_SCOPE_AGENT);
}

// Row permutation: r' = mt*16 + quad*4 + reg  ->  channel = r'>>2, gate = r'&3.
// orig torch row = gate*Hch + channel. One lane of the C-frag then holds one
// channel's (i,f,g,o) quad (C: col=lane&15, row=(lane>>4)*4+reg).

// Pack W (fp32 [4*Hch][Kdim], torch gate rows) into fp16 A-frag order:
// wp[(mt*KT+kt)*64+lane] = 8 halves of W'[mt*16+(lane&15)][kt*32+(lane>>4)*8+j]
__global__ __launch_bounds__(256) void pack_frag(const float* __restrict__ w,
    uint4* __restrict__ wp, int Hch, int Kdim, int MT, int KT) {
  int o = blockIdx.x * 256 + threadIdx.x;
  if (o >= MT * KT * 64) return;
  int lane = o & 63, fk = o >> 6;
  int kt = fk % KT, mt = fk / KT;
  int rp = mt * 16 + (lane & 15);
  int orig = (rp & 3) * Hch + (rp >> 2);
  int k0 = kt * 32 + (lane >> 4) * 8;
  unsigned r[4];
#pragma unroll
  for (int p = 0; p < 4; ++p) {
    unsigned lo = __half_as_ushort(__float2half_rn(w[(size_t)orig * Kdim + k0 + 2 * p]));
    unsigned hi = __half_as_ushort(__float2half_rn(w[(size_t)orig * Kdim + k0 + 2 * p + 1]));
    r[p] = lo | (hi << 16);
  }
  uint4 v; v.x = r[0]; v.y = r[1]; v.z = r[2]; v.w = r[3];
  wp[o] = v;
}

__global__ __launch_bounds__(256) void pack_bias(const float* __restrict__ bih,
    const float* __restrict__ bhh, float* __restrict__ bs, int Hch) {
  int rp = blockIdx.x * 256 + threadIdx.x;
  if (rp >= 4 * Hch) return;
  int orig = (rp & 3) * Hch + (rp >> 2);
  bs[rp] = bih[orig] + bhh[orig];
}

__global__ void pack_wl(const float* __restrict__ wl, unsigned* __restrict__ wlp, int n) {
  int i = threadIdx.x;
  if (i < n) {
    unsigned lo = __half_as_ushort(__float2half_rn(wl[2 * i]));
    unsigned hi = __half_as_ushort(__float2half_rn(wl[2 * i + 1]));
    wlp[i] = lo | (hi << 16);
  }
}

__global__ __launch_bounds__(256) void f2h(const float* __restrict__ x,
                                           __half* __restrict__ y, int n8) {
  int i = blockIdx.x * 256 + threadIdx.x;
  if (i >= n8) return;
  float4 a = *(const float4*)(x + i * 8);
  float4 b = *(const float4*)(x + i * 8 + 4);
  __half h[8];
  h[0] = __float2half_rn(a.x); h[1] = __float2half_rn(a.y);
  h[2] = __float2half_rn(a.z); h[3] = __float2half_rn(a.w);
  h[4] = __float2half_rn(b.x); h[5] = __float2half_rn(b.y);
  h[6] = __float2half_rn(b.z); h[7] = __float2half_rn(b.w);
  *(uint4*)(y + i * 8) = *(const uint4*)h;
}

// K-block over a compile-time k-tile range reading B-frags from buffer BUF.
#define KBLK(BUF, K0, K1)                                                           \
  _Pragma("unroll") for (int kt = (K0); kt < (K1); ++kt) {                          \
    f16x8 bfrag = as_f16x8(*(const uint4*)((BUF) + n16 * HP + kt * 32 + quad * 8)); \
    _Pragma("unroll") for (int im = 0; im < MTW; ++im)                              \
      acc[im] = __builtin_amdgcn_mfma_f32_16x16x32_f16(                             \
          as_f16x8(areg[im][kt]), bfrag, acc[im], 0, 0, 0);                         \
  }

// One layer-stage: embedded input GEMM (own m-tiles, whole chunk -> preT)
// followed by the weight-stationary recurrent scan. hb DOUBLE-BUFFERED:
// SPLIT=1 -> 1 barrier/step; SPLIT=2 -> 2 barriers/step + flagless seq-tagged
// cross-WG h exchange with SPECULATIVE import (loads issued before the
// own-half MFMAs so the mall round-trip hides under them).
template <int H, int SPLIT, bool FINAL, int KTI>
DEVINL void scan_body(
    int bx, const __half* x, const uint4* wpI, const float* bs,
    const uint4* wp, f32x4* preT, __half* xout, float* out,
    const unsigned* wlp, const float* blp,
    float* sth, float* stc, unsigned long long* xh,
    int Sc, int t0, int first) {
  constexpr int MT = H / 4;          // total m-tiles
  constexpr int MTO = MT / SPLIT;    // owned m-tiles
  constexpr int MTW = MTO / 8;       // per wave
  constexpr int KT = H / 32;
  constexpr int HP = H + 8;
  constexpr int CH_OWN = MTO * 4;    // owned channels

  __shared__ __half hb[2][16 * HP];
  __shared__ unsigned wls[FINAL ? H / 2 : 1];

  const int tid = threadIdx.x, w = tid >> 6, lane = tid & 63;
  const int n16 = lane & 15, quad = lane >> 4;
  int bt, half;
  if constexpr (SPLIT == 2) { bt = bx & 15; half = bx >> 4; }
  else { bt = bx; half = 0; }
  const int b0 = bt * 16;
  const int mbase = half * MTO;

  // ---- embedded input GEMM: preT for own m-tiles, all Sc timesteps ----
  {
    constexpr int KI = KTI * 32;
    uint4 wih[MTW][KTI];
#pragma unroll
    for (int im = 0; im < MTW; ++im)
#pragma unroll
      for (int kt = 0; kt < KTI; ++kt)
        wih[im][kt] = wpI[((size_t)(mbase + w * MTW + im) * KTI + kt) * 64 + lane];
    f32x4 bini[MTW];
#pragma unroll
    for (int im = 0; im < MTW; ++im)
      bini[im] = *(const f32x4*)(bs + (mbase + w * MTW + im) * 16 + quad * 4);
    uint4 bfr[KTI];
    {
      const __half* xr = x + ((size_t)(b0 + n16) * S + t0) * KI + quad * 8;
#pragma unroll
      for (int kt = 0; kt < KTI; ++kt) bfr[kt] = *(const uint4*)(xr + kt * 32);
    }
    for (int t = 0; t < Sc; ++t) {
      uint4 cur[KTI];
#pragma unroll
      for (int kt = 0; kt < KTI; ++kt) cur[kt] = bfr[kt];
      if (t + 1 < Sc) {  // prefetch next timestep's B-frags
        const __half* xr = x + ((size_t)(b0 + n16) * S + t0 + t + 1) * KI + quad * 8;
#pragma unroll
        for (int kt = 0; kt < KTI; ++kt) bfr[kt] = *(const uint4*)(xr + kt * 32);
      }
      f32x4 ac[MTW];
#pragma unroll
      for (int im = 0; im < MTW; ++im) ac[im] = bini[im];
#pragma unroll
      for (int kt = 0; kt < KTI; ++kt)
#pragma unroll
        for (int im = 0; im < MTW; ++im)
          ac[im] = __builtin_amdgcn_mfma_f32_16x16x32_f16(as_f16x8(wih[im][kt]),
                                                          as_f16x8(cur[kt]), ac[im], 0, 0, 0);
#pragma unroll
      for (int im = 0; im < MTW; ++im)
        preT[((size_t)(bt * Sc + t) * MT + mbase + w * MTW + im) * 64 + lane] = ac[im];
    }
  }
  // own preT writes must be at L2 before this wave re-reads them below
  asm volatile("s_waitcnt vmcnt(0)" ::: "memory");

  // ---- scan phase ----
  uint4 areg[MTW][KT];
#pragma unroll
  for (int im = 0; im < MTW; ++im)
#pragma unroll
    for (int kt = 0; kt < KT; ++kt)
      areg[im][kt] = wp[((size_t)(mbase + w * MTW + im) * KT + kt) * 64 + lane];

  if constexpr (FINAL)
    for (int i = tid; i < H / 2; i += 512) wls[i] = wlp[i];

  float cst[MTW];
#pragma unroll
  for (int im = 0; im < MTW; ++im) {
    int ch = (mbase + w * MTW + im) * 4 + quad;
    cst[im] = first ? 0.f : stc[(size_t)(b0 + n16) * H + ch];
  }
  for (int i = tid; i < 16 * H; i += 512) {
    int n = i / H, ch = i % H;
    hb[0][n * HP + ch] = first ? __float2half_rn(0.f)
                               : __float2half_rn(sth[(size_t)(b0 + n) * H + ch]);
  }
  __syncthreads();

  const float bl0 = FINAL ? blp[0] : 0.f;

  auto emit_out = [&](const __half* rbuf, int t_out) {
    if constexpr (FINAL) {
      if ((SPLIT == 1 || half == 0) && tid < 128) {
        int n = tid >> 3, seg = tid & 7;
        const unsigned* hrow = (const unsigned*)(rbuf + n * HP);
        float s = 0.f;
#pragma unroll
        for (int p = 0; p < 16; ++p) s = fdot2(hrow[seg * 16 + p], wls[seg * 16 + p], s);
        s += __shfl_xor(s, 1); s += __shfl_xor(s, 2); s += __shfl_xor(s, 4);
        if (seg == 0) out[(size_t)(b0 + n) * S + t_out] = ftanh_(s + bl0);
      }
    } else {
      if (tid < 16 * (H / 8)) {
        int n = tid / (H / 8), kq = tid % (H / 8);
        uint4 v = *(const uint4*)(rbuf + n * HP + kq * 8);
        *(uint4*)(xout + ((size_t)(b0 + n) * S + t_out) * H + kq * 8) = v;
      }
    }
  };

  f32x4 nxt[MTW];
#pragma unroll
  for (int im = 0; im < MTW; ++im)
    nxt[im] = preT[((size_t)(bt * Sc) * MT + mbase + w * MTW + im) * 64 + lane];

  for (int tl = 0; tl < Sc; ++tl) {
    __half* rb = hb[tl & 1];        // holds h(tl-1)
    __half* wb = hb[(tl + 1) & 1];  // receives h(tl)
    f32x4 acc[MTW];
#pragma unroll
    for (int im = 0; im < MTW; ++im) acc[im] = nxt[im];
    if (tl + 1 < Sc) {  // prefetch next step's preT
#pragma unroll
      for (int im = 0; im < MTW; ++im)
        nxt[im] = preT[((size_t)(bt * Sc + tl + 1) * MT + mbase + w * MTW + im) * 64 + lane];
    }

    if constexpr (SPLIT == 2) {
      // speculative import of peer half of h(tl-1): issue loads NOW, validate
      // after the own-half MFMAs (mall round-trip hides under them).
      unsigned long long v0 = 0, v1 = 0;
      unsigned long long* src = nullptr;
      const unsigned seq = (unsigned)(t0 + tl);  // (hid = t0+tl-1) + 1
      const int j0 = w * 128 + lane;
      if (tl > 0) {
        src = xh + (((size_t)((t0 + tl - 1) & 1) * 16 + bt) * 2 + (1 - half)) * 1024;
        v0 = agldull(src + j0);
        v1 = agldull(src + j0 + 64);
      }
      if (half == 0) { KBLK(rb, 0, KT / 2) } else { KBLK(rb, KT / 2, KT) }
      if (tl > 0) {
        for (;;) {
          bool ok = ((unsigned)(v0 >> 32) == seq) & ((unsigned)(v1 >> 32) == seq);
          if (__all(ok)) break;
          __builtin_amdgcn_s_sleep(1);
          v0 = agldull(src + j0);
          v1 = agldull(src + j0 + 64);
        }
        int c0 = j0 >> 3, dn0 = j0 & 7;  // dword j = c*8 + dn; batches 2dn,2dn+1
        rb[(2 * dn0) * HP + (1 - half) * CH_OWN + c0] =
            __ushort_as_half((unsigned short)(v0 & 0xffffu));
        rb[(2 * dn0 + 1) * HP + (1 - half) * CH_OWN + c0] =
            __ushort_as_half((unsigned short)((v0 >> 16) & 0xffffu));
        int j1 = j0 + 64, c1 = j1 >> 3, dn1 = j1 & 7;
        rb[(2 * dn1) * HP + (1 - half) * CH_OWN + c1] =
            __ushort_as_half((unsigned short)(v1 & 0xffffu));
        rb[(2 * dn1 + 1) * HP + (1 - half) * CH_OWN + c1] =
            __ushort_as_half((unsigned short)((v1 >> 16) & 0xffffu));
        __syncthreads();  // [#1] peer half of h(tl-1) visible
      }
      if (half == 0) { KBLK(rb, KT / 2, KT) } else { KBLK(rb, 0, KT / 2) }
      if (tl > 0) emit_out(rb, t0 + tl - 1);  // full h(tl-1) in rb
    } else {
      if (tl > 0) emit_out(rb, t0 + tl - 1);
      KBLK(rb, 0, KT)
    }

    // gates (lane holds one channel's i,f,g,o per m-tile)
    __half hh[MTW];
#pragma unroll
    for (int im = 0; im < MTW; ++im) {
      float gi = fsig(acc[im][0]);
      float gf = fsig(acc[im][1]);
      float gg = ftanh_(acc[im][2]);
      float go = fsig(acc[im][3]);
      float cn = gf * cst[im] + gi * gg;
      cst[im] = cn;
      hh[im] = __float2half_rn(go * ftanh_(cn));
    }

    if constexpr (SPLIT == 2) {
      // export h(tl): lanes (2k,2k+1) pack one dword via shfl_xor(1), tagged.
      const int hid = t0 + tl;
      const unsigned eseq = (unsigned)(hid + 1);
      unsigned long long* dst =
          xh + (((size_t)(hid & 1) * 16 + bt) * 2 + half) * 1024;
#pragma unroll
      for (int im = 0; im < MTW; ++im) {
        unsigned m = (unsigned)__half_as_ushort(hh[im]);
        unsigned o = (unsigned)__shfl_xor((int)m, 1);
        if (!(lane & 1)) {
          int cl = (w * MTW + im) * 4 + quad;  // channel local to this half
          agstull(dst + cl * 8 + (n16 >> 1),
                  ((unsigned long long)eseq << 32) | (unsigned long long)(m | (o << 16)));
        }
      }
#pragma unroll
      for (int im = 0; im < MTW; ++im)
        wb[n16 * HP + (mbase + w * MTW + im) * 4 + quad] = hh[im];
      __syncthreads();  // [#2] own half of h(tl) ready; rb reads all done
    } else {
#pragma unroll
      for (int im = 0; im < MTW; ++im)
        wb[n16 * HP + (mbase + w * MTW + im) * 4 + quad] = hh[im];
      __syncthreads();  // single barrier/step (double-buffered hb)
    }
  }

  __half* fb = hb[Sc & 1];  // holds own half of h(Sc-1)
  if constexpr (SPLIT == 2) {
    // tail: import peer half of h(Sc-1) for output + state carry
    const unsigned seq = (unsigned)(t0 + Sc);
    unsigned long long* src =
        xh + (((size_t)((t0 + Sc - 1) & 1) * 16 + bt) * 2 + (1 - half)) * 1024;
    const int j0 = w * 128 + lane;
    unsigned long long v0 = agldull(src + j0), v1 = agldull(src + j0 + 64);
    for (;;) {
      bool ok = ((unsigned)(v0 >> 32) == seq) & ((unsigned)(v1 >> 32) == seq);
      if (__all(ok)) break;
      __builtin_amdgcn_s_sleep(1);
      v0 = agldull(src + j0);
      v1 = agldull(src + j0 + 64);
    }
    int c0 = j0 >> 3, dn0 = j0 & 7;
    fb[(2 * dn0) * HP + (1 - half) * CH_OWN + c0] =
        __ushort_as_half((unsigned short)(v0 & 0xffffu));
    fb[(2 * dn0 + 1) * HP + (1 - half) * CH_OWN + c0] =
        __ushort_as_half((unsigned short)((v0 >> 16) & 0xffffu));
    int j1 = j0 + 64, c1 = j1 >> 3, dn1 = j1 & 7;
    fb[(2 * dn1) * HP + (1 - half) * CH_OWN + c1] =
        __ushort_as_half((unsigned short)(v1 & 0xffffu));
    fb[(2 * dn1 + 1) * HP + (1 - half) * CH_OWN + c1] =
        __ushort_as_half((unsigned short)((v1 >> 16) & 0xffffu));
    __syncthreads();
  }

  emit_out(fb, t0 + Sc - 1);

  // carry state (sth full range — duplicate identical writes for SPLIT=2 benign)
  for (int i = tid; i < 16 * H; i += 512) {
    int n = i / H, ch = i % H;
    sth[(size_t)(b0 + n) * H + ch] = __half2float(fb[n * HP + ch]);
  }
#pragma unroll
  for (int im = 0; im < MTW; ++im) {
    int ch = (mbase + w * MTW + im) * 4 + quad;
    stc[(size_t)(b0 + n16) * H + ch] = cst[im];
  }
}
#undef KBLK

// Fat pipelined kernel: slot s runs L0(chunk s), L1(chunk s-1), L2(chunk s-2)
// concurrently as disjoint WG ranges. Inter-layer deps are carried by dispatch
// order only (x1/x2 produced in slot s, consumed in slot s+1).
__global__ __launch_bounds__(512) void scan_fat(
    const __half* x0, __half* x1, __half* x2,
    const uint4* wpI0, const uint4* wpI1, const uint4* wpI2,
    const float* bs0, const float* bs1, const float* bs2,
    const uint4* wpH0, const uint4* wpH1, const uint4* wpH2,
    f32x4* preT0, f32x4* preT1, f32x4* preT2,
    float* out, const unsigned* wlp, const float* blp,
    float* sh0, float* sc0, float* sh1, float* sc1, float* sh2, float* sc2,
    unsigned long long* xh, int Sc, int slot, int NC) {
  int b = blockIdx.x;
  if (b < 16) {
    int c = slot;
    if (c >= NC) return;
    scan_body<64, 1, false, 1>(b, x0, wpI0, bs0, wpH0, preT0, x1, nullptr,
                               nullptr, nullptr, sh0, sc0, nullptr, Sc, c * Sc, c == 0);
  } else if (b < 32) {
    int c = slot - 1;
    if (c < 0 || c >= NC) return;
    scan_body<128, 1, false, 2>(b - 16, x1, wpI1, bs1, wpH1, preT1, x2, nullptr,
                                nullptr, nullptr, sh1, sc1, nullptr, Sc, c * Sc, c == 0);
  } else {
    int c = slot - 2;
    if (c < 0 || c >= NC) return;
    scan_body<256, 2, true, 4>(b - 32, x2, wpI2, bs2, wpH2, preT2, nullptr, out,
                               wlp, blp, sh2, sc2, xh, Sc, c * Sc, c == 0);
  }
}

extern "C" void kernel_launch(void* const* d_in, const int* in_sizes, int n_in,
                              void* d_out, int out_size, void* d_ws, size_t ws_size,
                              hipStream_t stream) {
  (void)in_sizes; (void)n_in; (void)out_size;
  const float* noise = (const float*)d_in[0];
  const float* Wih0 = (const float*)d_in[1];
  const float* Whh0 = (const float*)d_in[2];
  const float* bih0 = (const float*)d_in[3];
  const float* bhh0 = (const float*)d_in[4];
  const float* Wih1 = (const float*)d_in[5];
  const float* Whh1 = (const float*)d_in[6];
  const float* bih1 = (const float*)d_in[7];
  const float* bhh1 = (const float*)d_in[8];
  const float* Wih2 = (const float*)d_in[9];
  const float* Whh2 = (const float*)d_in[10];
  const float* bih2 = (const float*)d_in[11];
  const float* bhh2 = (const float*)d_in[12];
  const float* Wl = (const float*)d_in[13];
  const float* bl = (const float*)d_in[14];
  float* out = (float*)d_out;

  char* p = (char*)d_ws;
  auto alloc = [&](size_t bytes) {
    char* r = p;
    p += (bytes + 255) & ~(size_t)255;
    return r;
  };
  // A-frag packed weights (fp16): recurrent + input
  uint4* wpH0 = (uint4*)alloc((size_t)16 * 2 * 1024);
  uint4* wpH1 = (uint4*)alloc((size_t)32 * 4 * 1024);
  uint4* wpH2 = (uint4*)alloc((size_t)64 * 8 * 1024);
  uint4* wpI0 = (uint4*)alloc((size_t)16 * 1 * 1024);
  uint4* wpI1 = (uint4*)alloc((size_t)32 * 2 * 1024);
  uint4* wpI2 = (uint4*)alloc((size_t)64 * 4 * 1024);
  float* bs0 = (float*)alloc(256 * 4);
  float* bs1 = (float*)alloc(512 * 4);
  float* bs2 = (float*)alloc(1024 * 4);
  unsigned* wlp = (unsigned*)alloc(128 * 4);
  // state carry
  float* sh0 = (float*)alloc((size_t)B * H0 * 4);
  float* sc0 = (float*)alloc((size_t)B * H0 * 4);
  float* sh1 = (float*)alloc((size_t)B * H1 * 4);
  float* sc1 = (float*)alloc((size_t)B * H1 * 4);
  float* sh2 = (float*)alloc((size_t)B * H2 * 4);
  float* sc2 = (float*)alloc((size_t)B * H2 * 4);
  // activations (fp16)
  __half* x0 = (__half*)alloc((size_t)B * S * 32 * 2);
  __half* x1 = (__half*)alloc((size_t)B * S * H0 * 2);
  __half* x2 = (__half*)alloc((size_t)B * S * H1 * 2);
  // cross-WG exchange: {seq|data} ull per dword-pair, 2 parity x 16 bt x 2 half
  unsigned long long* xh = (unsigned long long*)alloc((size_t)2 * 16 * 2 * 1024 * 8);
  size_t fixed = (size_t)(p - (char*)d_ws);
  int Sc = 64;  // chunk size; per-layer preT buffers hold ONE chunk each
  while (Sc > 16 && fixed + (size_t)B * Sc * 16 * (H0 + H1 + H2) > ws_size) Sc >>= 1;
  f32x4* preT0 = (f32x4*)alloc((size_t)B * Sc * 16 * H0);
  f32x4* preT1 = (f32x4*)alloc((size_t)B * Sc * 16 * H1);
  f32x4* preT2 = (f32x4*)alloc((size_t)B * Sc * 16 * H2);

  // xh must be zeroed each launch: seq values repeat across graph replays and
  // inputs may be re-poisoned, so stale {seq|data} would validate wrongly.
  hipMemsetAsync(xh, 0, (size_t)2 * 16 * 2 * 1024 * 8, stream);

  // ---- packing (every call; deterministic) ----
  pack_frag<<<(16 * 2 * 64 + 255) / 256, 256, 0, stream>>>(Whh0, wpH0, 64, 64, 16, 2);
  pack_frag<<<(32 * 4 * 64 + 255) / 256, 256, 0, stream>>>(Whh1, wpH1, 128, 128, 32, 4);
  pack_frag<<<(64 * 8 * 64 + 255) / 256, 256, 0, stream>>>(Whh2, wpH2, 256, 256, 64, 8);
  pack_frag<<<(16 * 1 * 64 + 255) / 256, 256, 0, stream>>>(Wih0, wpI0, 64, 32, 16, 1);
  pack_frag<<<(32 * 2 * 64 + 255) / 256, 256, 0, stream>>>(Wih1, wpI1, 128, 64, 32, 2);
  pack_frag<<<(64 * 4 * 64 + 255) / 256, 256, 0, stream>>>(Wih2, wpI2, 256, 128, 64, 4);
  pack_bias<<<1, 256, 0, stream>>>(bih0, bhh0, bs0, 64);
  pack_bias<<<2, 256, 0, stream>>>(bih1, bhh1, bs1, 128);
  pack_bias<<<4, 256, 0, stream>>>(bih2, bhh2, bs2, 256);
  pack_wl<<<1, 128, 0, stream>>>(Wl, wlp, 128);
  f2h<<<(B * S * 32 / 8 + 255) / 256, 256, 0, stream>>>(noise, x0, B * S * 32 / 8);

  // ---- pipelined slots: L0(c=s) || L1(c=s-1) || L2(c=s-2) ----
  int NC = S / Sc;
  for (int slot = 0; slot < NC + 2; ++slot)
    scan_fat<<<64, 512, 0, stream>>>(x0, x1, x2, wpI0, wpI1, wpI2, bs0, bs1, bs2,
                                     wpH0, wpH1, wpH2, preT0, preT1, preT2,
                                     out, wlp, bl, sh0, sc0, sh1, sc1, sh2, sc2,
                                     xh, Sc, slot, NC);
}